// Round 1
// baseline (3159.130 us; speedup 1.0000x reference)
//
#include <hip/hip_runtime.h>

#define EPSF 1e-5f

__device__ __forceinline__ float elu_f(float x) { return x > 0.f ? x : expm1f(x); }

// ---------------- degree / norm precompute ----------------

__global__ __launch_bounds__(256) void k_init_deg(float* deg, int n) {
    int i = blockIdx.x * 256 + threadIdx.x;
    if (i < n) deg[i] = 1.0f;   // self-loop contributes 1
}

__global__ __launch_bounds__(256) void k_edge_deg(const int* __restrict__ dst, float* deg, int E) {
    int e = blockIdx.x * 256 + threadIdx.x;
    if (e < E) atomicAdd(&deg[dst[e]], 1.0f);
}

__global__ __launch_bounds__(256) void k_dinv(float* deg, int n) {
    int i = blockIdx.x * 256 + threadIdx.x;
    if (i < n) deg[i] = rsqrtf(deg[i]);   // deg >= 1 always (self-loop)
}

__global__ __launch_bounds__(256) void k_norm(const int* __restrict__ src, const int* __restrict__ dst,
                                              const float* __restrict__ dinv, float* __restrict__ norm, int E) {
    int e = blockIdx.x * 256 + threadIdx.x;
    if (e < E) norm[e] = dinv[src[e]] * dinv[dst[e]];
}

// ---------------- self-loop + bias init of aggregation buffer ----------------
// out[i][f] = (HASB ? b[f] : 0) + in[i][f] * dinv[i]^2   (vectorized float4)
template<int F, bool HASB>
__global__ __launch_bounds__(256) void k_selfinit(const float* __restrict__ in, const float* __restrict__ b,
                                                  const float* __restrict__ dinv, float* __restrict__ out, int n) {
    constexpr int C = F / 4;
    long tid = (long)blockIdx.x * 256 + threadIdx.x;
    long total = (long)n * C;
    if (tid >= total) return;
    int i = (int)(tid / C);
    int c = (int)(tid % C);
    float di = dinv[i];
    float sn = di * di;
    float4 v = reinterpret_cast<const float4*>(in)[tid];
    float4 o;
    if (HASB) {
        float4 bb = reinterpret_cast<const float4*>(b)[c];
        o.x = bb.x + v.x * sn; o.y = bb.y + v.y * sn;
        o.z = bb.z + v.z * sn; o.w = bb.w + v.w * sn;
    } else {
        o.x = v.x * sn; o.y = v.y * sn; o.z = v.z * sn; o.w = v.w * sn;
    }
    reinterpret_cast<float4*>(out)[tid] = o;
}

// ---------------- edge scatter-aggregate: out[dst] += in[src] * norm ----------------
template<int F>
__global__ __launch_bounds__(256) void k_edge_agg(const int* __restrict__ src, const int* __restrict__ dst,
                                                  const float* __restrict__ norm, const float* __restrict__ xin,
                                                  float* __restrict__ out, int E) {
    constexpr int C = F / 4;
    long tid = (long)blockIdx.x * 256 + threadIdx.x;
    long total = (long)E * C;
    if (tid >= total) return;
    int e = (int)(tid / C);
    int c = (int)(tid % C);
    int s = src[e], d = dst[e];
    float nr = norm[e];
    float4 v = reinterpret_cast<const float4*>(xin + (long)s * F)[c];
    float* op = out + (long)d * F + c * 4;
    atomicAdd(op + 0, v.x * nr);
    atomicAdd(op + 1, v.y * nr);
    atomicAdd(op + 2, v.z * nr);
    atomicAdd(op + 3, v.w * nr);
}

// scalar (F=1) variant for layer 4
__global__ __launch_bounds__(256) void k_edge_agg1(const int* __restrict__ src, const int* __restrict__ dst,
                                                   const float* __restrict__ norm, const float* __restrict__ y,
                                                   float* __restrict__ out, int E) {
    int e = blockIdx.x * 256 + threadIdx.x;
    if (e < E) atomicAdd(out + dst[e], y[src[e]] * norm[e]);
}

__global__ __launch_bounds__(256) void k_selfinit1(const float* __restrict__ y, const float* __restrict__ b,
                                                   const float* __restrict__ dinv, float* __restrict__ out, int n) {
    int i = blockIdx.x * 256 + threadIdx.x;
    if (i < n) {
        float di = dinv[i];
        out[i] = b[0] + y[i] * di * di;
    }
}

// ---------------- BN(eval)+ELU standalone (layer 1 post-aggregation) ----------------
template<int F>
__global__ __launch_bounds__(256) void k_bnelu(const float* __restrict__ in, const float* __restrict__ g,
                                               const float* __restrict__ be, const float* __restrict__ rm,
                                               const float* __restrict__ rv, float* __restrict__ out, int n) {
    constexpr int C = F / 4;
    long tid = (long)blockIdx.x * 256 + threadIdx.x;
    long total = (long)n * C;
    if (tid >= total) return;
    int c = (int)(tid % C);
    float4 v  = reinterpret_cast<const float4*>(in)[tid];
    float4 gg = reinterpret_cast<const float4*>(g)[c];
    float4 bb = reinterpret_cast<const float4*>(be)[c];
    float4 mm = reinterpret_cast<const float4*>(rm)[c];
    float4 vv = reinterpret_cast<const float4*>(rv)[c];
    float4 o;
    o.x = elu_f((v.x - mm.x) * rsqrtf(vv.x + EPSF) * gg.x + bb.x);
    o.y = elu_f((v.y - mm.y) * rsqrtf(vv.y + EPSF) * gg.y + bb.y);
    o.z = elu_f((v.z - mm.z) * rsqrtf(vv.z + EPSF) * gg.z + bb.z);
    o.w = elu_f((v.w - mm.w) * rsqrtf(vv.w + EPSF) * gg.w + bb.w);
    reinterpret_cast<float4*>(out)[tid] = o;
}

// ---------------- small dense GEMM: Y = X @ W (+ optional bias+BN+ELU epilogue) ----------------
// block = 256 threads; thread = (local row, fout); W staged in LDS.
template<int DIN, int DOUT, bool BN>
__global__ __launch_bounds__(256) void k_gemm(const float* __restrict__ X, const float* __restrict__ W,
                                              const float* __restrict__ b, const float* __restrict__ g,
                                              const float* __restrict__ be, const float* __restrict__ rm,
                                              const float* __restrict__ rv, float* __restrict__ Y, int n) {
    __shared__ float Wl[DIN * DOUT];
    for (int idx = threadIdx.x; idx < DIN * DOUT; idx += 256) Wl[idx] = W[idx];
    __syncthreads();
    constexpr int ROWS = 256 / DOUT;
    int fout = threadIdx.x % DOUT;
    int rloc = threadIdx.x / DOUT;
    float scale = 1.f, shift = 0.f, bias = 0.f;
    if (BN) {
        float inv = rsqrtf(rv[fout] + EPSF);
        scale = g[fout] * inv;
        shift = be[fout] - rm[fout] * scale;
        bias = b[fout];
    }
    long row = (long)blockIdx.x * ROWS + rloc;
    if (row >= n) return;
    const float* xr = X + row * DIN;
    float acc = 0.f;
    #pragma unroll
    for (int k = 0; k < DIN; k += 4) {
        float4 xv = *reinterpret_cast<const float4*>(xr + k);
        acc += xv.x * Wl[(k + 0) * DOUT + fout];
        acc += xv.y * Wl[(k + 1) * DOUT + fout];
        acc += xv.z * Wl[(k + 2) * DOUT + fout];
        acc += xv.w * Wl[(k + 3) * DOUT + fout];
    }
    float v = acc;
    if (BN) {
        v = (acc + bias) * scale + shift;
        v = elu_f(v);
    }
    Y[row * DOUT + fout] = v;
}

// 128 -> 1 dot product per row: 32 lanes per row, float4 per lane, shuffle reduce.
__global__ __launch_bounds__(256) void k_dot128(const float* __restrict__ X, const float* __restrict__ W4,
                                                float* __restrict__ Y, int n) {
    long tid = (long)blockIdx.x * 256 + threadIdx.x;
    int row = (int)(tid >> 5);
    int part = (int)(tid & 31);
    if (row >= n) return;
    float4 xv = reinterpret_cast<const float4*>(X + (long)row * 128)[part];
    float4 wv = reinterpret_cast<const float4*>(W4)[part];
    float s = xv.x * wv.x + xv.y * wv.y + xv.z * wv.z + xv.w * wv.w;
    #pragma unroll
    for (int m = 16; m >= 1; m >>= 1) s += __shfl_xor(s, m, 64);
    if (part == 0) Y[row] = s;
}

__global__ __launch_bounds__(256) void k_final(const float* __restrict__ in, float* __restrict__ out, int n) {
    int i = blockIdx.x * 256 + threadIdx.x;
    if (i < n) {
        float v = elu_f(in[i]);
        out[i] = 1.f / (1.f + expf(-v));
    }
}

// ---------------- launch ----------------

extern "C" void kernel_launch(void* const* d_in, const int* in_sizes, int n_in,
                              void* d_out, int out_size, void* d_ws, size_t ws_size,
                              hipStream_t stream) {
    const float* x   = (const float*)d_in[0];
    const int*   edg = (const int*)d_in[1];
    const float* W1 = (const float*)d_in[2];
    const float* b1 = (const float*)d_in[3];
    const float* W2 = (const float*)d_in[4];
    const float* b2 = (const float*)d_in[5];
    const float* W3 = (const float*)d_in[6];
    const float* b3 = (const float*)d_in[7];
    const float* W4 = (const float*)d_in[8];
    const float* b4 = (const float*)d_in[9];
    const float* g1  = (const float*)d_in[10];
    const float* be1 = (const float*)d_in[11];
    const float* rm1 = (const float*)d_in[12];
    const float* rv1 = (const float*)d_in[13];
    const float* g2  = (const float*)d_in[14];
    const float* be2 = (const float*)d_in[15];
    const float* rm2 = (const float*)d_in[16];
    const float* rv2 = (const float*)d_in[17];
    const float* g3  = (const float*)d_in[18];
    const float* be3 = (const float*)d_in[19];
    const float* rm3 = (const float*)d_in[20];
    const float* rv3 = (const float*)d_in[21];
    float* out = (float*)d_out;

    const int N = in_sizes[0] / 64;
    const int E = in_sizes[1] / 2;
    const int* src = edg;
    const int* dst = edg + E;

    float* dinv = (float*)d_ws;          // N
    float* norm = dinv + N;              // E
    float* A    = norm + E;              // N*128
    float* B    = A + (size_t)N * 128;   // N*128

    auto nb = [](long total) { return (int)((total + 255) / 256); };

    // degree / dinv / per-edge norm (shared across layers)
    k_init_deg<<<nb(N), 256, 0, stream>>>(dinv, N);
    k_edge_deg<<<nb(E), 256, 0, stream>>>(dst, dinv, E);
    k_dinv<<<nb(N), 256, 0, stream>>>(dinv, N);
    k_norm<<<nb(E), 256, 0, stream>>>(src, dst, dinv, norm, E);

    // Layer 1 (64->32): GEMM first, aggregate 32 feats, then BN+ELU
    k_gemm<64, 32, false><<<(N + 7) / 8, 256, 0, stream>>>(x, W1, nullptr, nullptr, nullptr, nullptr, nullptr, A, N);
    k_selfinit<32, true><<<nb((long)N * 8), 256, 0, stream>>>(A, b1, dinv, B, N);
    k_edge_agg<32><<<nb((long)E * 8), 256, 0, stream>>>(src, dst, norm, A, B, E);
    k_bnelu<32><<<nb((long)N * 8), 256, 0, stream>>>(B, g1, be1, rm1, rv1, A, N);

    // Layer 2 (32->64): aggregate 32 feats first, then fused GEMM+bias+BN+ELU
    k_selfinit<32, false><<<nb((long)N * 8), 256, 0, stream>>>(A, nullptr, dinv, B, N);
    k_edge_agg<32><<<nb((long)E * 8), 256, 0, stream>>>(src, dst, norm, A, B, E);
    k_gemm<32, 64, true><<<(N + 3) / 4, 256, 0, stream>>>(B, W2, b2, g2, be2, rm2, rv2, A, N);

    // Layer 3 (64->128): aggregate 64 feats first, then fused GEMM+bias+BN+ELU
    k_selfinit<64, false><<<nb((long)N * 16), 256, 0, stream>>>(A, nullptr, dinv, B, N);
    k_edge_agg<64><<<nb((long)E * 16), 256, 0, stream>>>(src, dst, norm, A, B, E);
    k_gemm<64, 128, true><<<(N + 1) / 2, 256, 0, stream>>>(B, W3, b3, g3, be3, rm3, rv3, A, N);

    // Layer 4 (128->1): per-row dot first, aggregate scalar, then sigmoid(elu(.))
    k_dot128<<<nb((long)N * 32), 256, 0, stream>>>(A, W4, B, N);
    k_selfinit1<<<nb(N), 256, 0, stream>>>(B, b4, dinv, A, N);
    k_edge_agg1<<<nb(E), 256, 0, stream>>>(src, dst, norm, B, A, E);
    k_final<<<nb(N), 256, 0, stream>>>(A, out, N);
}

// Round 2
// 697.407 us; speedup vs baseline: 4.5298x; 4.5298x over previous
//
#include <hip/hip_runtime.h>

#define EPSF 1e-5f

__device__ __forceinline__ float elu_f(float x) { return x > 0.f ? x : expm1f(x); }

// ---------------- CSR build ----------------

__global__ __launch_bounds__(256) void k_zero(int* p, int n) {
    int i = blockIdx.x * 256 + threadIdx.x;
    if (i < n) p[i] = 0;
}

__global__ __launch_bounds__(256) void k_count(const int* __restrict__ dst, int* __restrict__ cnt, int E) {
    int e = blockIdx.x * 256 + threadIdx.x;
    if (e < E) atomicAdd(&cnt[dst[e]], 1);
}

#define SCAN_T 256
#define SCAN_E 4
#define SCAN_B (SCAN_T * SCAN_E)  // 1024 elems per block

__global__ __launch_bounds__(256) void k_scan1(const int* __restrict__ cnt, int* __restrict__ base,
                                               int* __restrict__ bsum, int n) {
    __shared__ int sh[SCAN_T];
    int t = threadIdx.x;
    int b0 = blockIdx.x * SCAN_B;
    int v[SCAN_E];
    int tsum = 0;
    #pragma unroll
    for (int j = 0; j < SCAN_E; ++j) {
        int idx = b0 + t * SCAN_E + j;
        v[j] = (idx < n) ? cnt[idx] : 0;
        tsum += v[j];
    }
    sh[t] = tsum;
    __syncthreads();
    for (int off = 1; off < SCAN_T; off <<= 1) {
        int add = (t >= off) ? sh[t - off] : 0;
        __syncthreads();
        sh[t] += add;
        __syncthreads();
    }
    int run = sh[t] - tsum;  // exclusive prefix of this thread
    if (t == SCAN_T - 1) bsum[blockIdx.x] = sh[t];
    #pragma unroll
    for (int j = 0; j < SCAN_E; ++j) {
        int idx = b0 + t * SCAN_E + j;
        if (idx < n) base[idx] = run;
        run += v[j];
    }
}

__global__ __launch_bounds__(256) void k_scan2(int* bsum, int nb) {
    __shared__ int sh[SCAN_T];
    int t = threadIdx.x;
    int v = (t < nb) ? bsum[t] : 0;
    sh[t] = v;
    __syncthreads();
    for (int off = 1; off < SCAN_T; off <<= 1) {
        int add = (t >= off) ? sh[t - off] : 0;
        __syncthreads();
        sh[t] += add;
        __syncthreads();
    }
    if (t < nb) bsum[t] = sh[t] - v;  // exclusive
}

__global__ __launch_bounds__(256) void k_scan3(int* base, const int* __restrict__ bsum, int n) {
    int i = blockIdx.x * 256 + threadIdx.x;
    if (i < n) base[i] += bsum[i / SCAN_B];
}

__global__ __launch_bounds__(256) void k_dinv(const int* __restrict__ cnt, float* __restrict__ dinv, int n) {
    int i = blockIdx.x * 256 + threadIdx.x;
    if (i < n) dinv[i] = rsqrtf((float)(cnt[i] + 1));  // +1 self-loop
}

__global__ __launch_bounds__(256) void k_fill(const int* __restrict__ src, const int* __restrict__ dst,
                                              const int* __restrict__ base, int* __restrict__ fcnt,
                                              const float* __restrict__ dinv,
                                              int* __restrict__ csr_src, float* __restrict__ csr_w, int E) {
    int e = blockIdx.x * 256 + threadIdx.x;
    if (e >= E) return;
    int d = dst[e];
    int s = src[e];
    int pos = base[d] + atomicAdd(&fcnt[d], 1);
    csr_src[pos] = s;
    csr_w[pos] = dinv[s];  // dinv[dst] hoisted into gather epilogue
}

// ---------------- CSR gather-aggregate ----------------
// out[i] = dinv_i * ( sum_e w_e * x[src_e] + dinv_i * x[i] )  [+ bias/BN/ELU epilogue]
template<int F, bool L1EPI>
__global__ __launch_bounds__(256) void k_gather(const int* __restrict__ base, const int* __restrict__ cnt,
                                                const int* __restrict__ csr_src, const float* __restrict__ csr_w,
                                                const float* __restrict__ dinv, const float* __restrict__ xin,
                                                const float* __restrict__ b, const float* __restrict__ g,
                                                const float* __restrict__ be, const float* __restrict__ rm,
                                                const float* __restrict__ rv, float* __restrict__ out, int n) {
    constexpr int C = F / 4;          // float4 lanes per node
    constexpr int NPB = 256 / C;      // nodes per block
    int lane = threadIdx.x % C;
    int nl = threadIdx.x / C;
    int i = blockIdx.x * NPB + nl;
    if (i >= n) return;
    int k = base[i];
    int kend = k + cnt[i];
    float di = dinv[i];
    const float4* X4 = reinterpret_cast<const float4*>(xin);
    float4 acc = {0.f, 0.f, 0.f, 0.f};
    float4 acc2 = {0.f, 0.f, 0.f, 0.f};
    for (; k + 1 < kend; k += 2) {
        int sa = csr_src[k];     float wa = csr_w[k];
        int sb = csr_src[k + 1]; float wb = csr_w[k + 1];
        float4 xa = X4[(long)sa * C + lane];
        float4 xb = X4[(long)sb * C + lane];
        acc.x += wa * xa.x; acc.y += wa * xa.y; acc.z += wa * xa.z; acc.w += wa * xa.w;
        acc2.x += wb * xb.x; acc2.y += wb * xb.y; acc2.z += wb * xb.z; acc2.w += wb * xb.w;
    }
    if (k < kend) {
        int sa = csr_src[k]; float wa = csr_w[k];
        float4 xa = X4[(long)sa * C + lane];
        acc.x += wa * xa.x; acc.y += wa * xa.y; acc.z += wa * xa.z; acc.w += wa * xa.w;
    }
    acc.x += acc2.x; acc.y += acc2.y; acc.z += acc2.z; acc.w += acc2.w;
    float4 xs = X4[(long)i * C + lane];
    float4 o;
    o.x = di * (acc.x + di * xs.x);
    o.y = di * (acc.y + di * xs.y);
    o.z = di * (acc.z + di * xs.z);
    o.w = di * (acc.w + di * xs.w);
    if (L1EPI) {
        float4 bb = reinterpret_cast<const float4*>(b)[lane];
        float4 gg = reinterpret_cast<const float4*>(g)[lane];
        float4 ee = reinterpret_cast<const float4*>(be)[lane];
        float4 mm = reinterpret_cast<const float4*>(rm)[lane];
        float4 vv = reinterpret_cast<const float4*>(rv)[lane];
        o.x = elu_f((o.x + bb.x - mm.x) * rsqrtf(vv.x + EPSF) * gg.x + ee.x);
        o.y = elu_f((o.y + bb.y - mm.y) * rsqrtf(vv.y + EPSF) * gg.y + ee.y);
        o.z = elu_f((o.z + bb.z - mm.z) * rsqrtf(vv.z + EPSF) * gg.z + ee.z);
        o.w = elu_f((o.w + bb.w - mm.w) * rsqrtf(vv.w + EPSF) * gg.w + ee.w);
    }
    reinterpret_cast<float4*>(out)[(long)i * C + lane] = o;
}

// scalar gather for layer 4 + final sigmoid(elu(.)) epilogue, writes d_out
__global__ __launch_bounds__(256) void k_gather1_final(const int* __restrict__ base, const int* __restrict__ cnt,
                                                       const int* __restrict__ csr_src, const float* __restrict__ csr_w,
                                                       const float* __restrict__ dinv, const float* __restrict__ y,
                                                       const float* __restrict__ b4, float* __restrict__ out, int n) {
    int i = blockIdx.x * 256 + threadIdx.x;
    if (i >= n) return;
    int k = base[i];
    int kend = k + cnt[i];
    float di = dinv[i];
    float acc = 0.f;
    for (; k < kend; ++k) acc += csr_w[k] * y[csr_src[k]];
    float v = di * (acc + di * y[i]) + b4[0];
    v = elu_f(v);
    out[i] = 1.f / (1.f + expf(-v));
}

// ---------------- small dense GEMM (+ optional bias+BN+ELU epilogue) ----------------
template<int DIN, int DOUT, bool BN>
__global__ __launch_bounds__(256) void k_gemm(const float* __restrict__ X, const float* __restrict__ W,
                                              const float* __restrict__ b, const float* __restrict__ g,
                                              const float* __restrict__ be, const float* __restrict__ rm,
                                              const float* __restrict__ rv, float* __restrict__ Y, int n) {
    __shared__ float Wl[DIN * DOUT];
    for (int idx = threadIdx.x; idx < DIN * DOUT; idx += 256) Wl[idx] = W[idx];
    __syncthreads();
    constexpr int ROWS = 256 / DOUT;
    int fout = threadIdx.x % DOUT;
    int rloc = threadIdx.x / DOUT;
    float scale = 1.f, shift = 0.f, bias = 0.f;
    if (BN) {
        float inv = rsqrtf(rv[fout] + EPSF);
        scale = g[fout] * inv;
        shift = be[fout] - rm[fout] * scale;
        bias = b[fout];
    }
    long row = (long)blockIdx.x * ROWS + rloc;
    if (row >= n) return;
    const float* xr = X + row * DIN;
    float acc = 0.f;
    #pragma unroll
    for (int k = 0; k < DIN; k += 4) {
        float4 xv = *reinterpret_cast<const float4*>(xr + k);
        acc += xv.x * Wl[(k + 0) * DOUT + fout];
        acc += xv.y * Wl[(k + 1) * DOUT + fout];
        acc += xv.z * Wl[(k + 2) * DOUT + fout];
        acc += xv.w * Wl[(k + 3) * DOUT + fout];
    }
    float v = acc;
    if (BN) {
        v = (acc + bias) * scale + shift;
        v = elu_f(v);
    }
    Y[row * DOUT + fout] = v;
}

// 128 -> 1 dot product per row: 32 lanes per row, float4 per lane, shuffle reduce.
__global__ __launch_bounds__(256) void k_dot128(const float* __restrict__ X, const float* __restrict__ W4,
                                                float* __restrict__ Y, int n) {
    long tid = (long)blockIdx.x * 256 + threadIdx.x;
    int row = (int)(tid >> 5);
    int part = (int)(tid & 31);
    if (row >= n) return;
    float4 xv = reinterpret_cast<const float4*>(X + (long)row * 128)[part];
    float4 wv = reinterpret_cast<const float4*>(W4)[part];
    float s = xv.x * wv.x + xv.y * wv.y + xv.z * wv.z + xv.w * wv.w;
    #pragma unroll
    for (int m = 16; m >= 1; m >>= 1) s += __shfl_xor(s, m, 64);
    if (part == 0) Y[row] = s;
}

// ---------------- launch ----------------

extern "C" void kernel_launch(void* const* d_in, const int* in_sizes, int n_in,
                              void* d_out, int out_size, void* d_ws, size_t ws_size,
                              hipStream_t stream) {
    const float* x   = (const float*)d_in[0];
    const int*   edg = (const int*)d_in[1];
    const float* W1 = (const float*)d_in[2];
    const float* b1 = (const float*)d_in[3];
    const float* W2 = (const float*)d_in[4];
    const float* b2 = (const float*)d_in[5];
    const float* W3 = (const float*)d_in[6];
    const float* b3 = (const float*)d_in[7];
    const float* W4 = (const float*)d_in[8];
    const float* b4 = (const float*)d_in[9];
    const float* g1  = (const float*)d_in[10];
    const float* be1 = (const float*)d_in[11];
    const float* rm1 = (const float*)d_in[12];
    const float* rv1 = (const float*)d_in[13];
    const float* g2  = (const float*)d_in[14];
    const float* be2 = (const float*)d_in[15];
    const float* rm2 = (const float*)d_in[16];
    const float* rv2 = (const float*)d_in[17];
    const float* g3  = (const float*)d_in[18];
    const float* be3 = (const float*)d_in[19];
    const float* rm3 = (const float*)d_in[20];
    const float* rv3 = (const float*)d_in[21];
    float* out = (float*)d_out;

    const int N = in_sizes[0] / 64;
    const int E = in_sizes[1] / 2;
    const int* src = edg;
    const int* dst = edg + E;
    const int NB_SCAN = (N + SCAN_B - 1) / SCAN_B;  // 98 for N=100000

    // workspace layout (all 16B-aligned by construction)
    int*   cnt     = (int*)d_ws;                    // N
    int*   fcnt    = cnt + N;                       // N
    int*   base    = fcnt + N;                      // N
    int*   bsum    = base + N;                      // 256
    int*   csr_src = bsum + 256;                    // E
    float* csr_w   = (float*)(csr_src + E);         // E
    float* dinv    = csr_w + E;                     // N
    float* A       = dinv + N;                      // N*64 max
    float* B       = A + (size_t)N * 64;            // N*128 max

    auto nb = [](long total) { return (int)((total + 255) / 256); };

    // CSR build (per call: inputs re-poisoned every launch)
    k_zero<<<nb(2L * N), 256, 0, stream>>>(cnt, 2 * N);              // cnt + fcnt contiguous
    k_count<<<nb(E), 256, 0, stream>>>(dst, cnt, E);
    k_scan1<<<NB_SCAN, 256, 0, stream>>>(cnt, base, bsum, N);
    k_scan2<<<1, 256, 0, stream>>>(bsum, NB_SCAN);
    k_scan3<<<nb(N), 256, 0, stream>>>(base, bsum, N);
    k_dinv<<<nb(N), 256, 0, stream>>>(cnt, dinv, N);
    k_fill<<<nb(E), 256, 0, stream>>>(src, dst, base, fcnt, dinv, csr_src, csr_w, E);

    // Layer 1 (64->32): GEMM, then gather-agg fused with bias+BN+ELU
    k_gemm<64, 32, false><<<(N + 7) / 8, 256, 0, stream>>>(x, W1, nullptr, nullptr, nullptr, nullptr, nullptr, A, N);
    k_gather<32, true><<<(N + 31) / 32, 256, 0, stream>>>(base, cnt, csr_src, csr_w, dinv, A,
                                                          b1, g1, be1, rm1, rv1, B, N);

    // Layer 2 (32->64): gather-agg first, then fused GEMM+bias+BN+ELU
    k_gather<32, false><<<(N + 31) / 32, 256, 0, stream>>>(base, cnt, csr_src, csr_w, dinv, B,
                                                           nullptr, nullptr, nullptr, nullptr, nullptr, A, N);
    k_gemm<32, 64, true><<<(N + 3) / 4, 256, 0, stream>>>(A, W2, b2, g2, be2, rm2, rv2, B, N);

    // Layer 3 (64->128): gather-agg first, then fused GEMM+bias+BN+ELU
    k_gather<64, false><<<(N + 15) / 16, 256, 0, stream>>>(base, cnt, csr_src, csr_w, dinv, B,
                                                           nullptr, nullptr, nullptr, nullptr, nullptr, A, N);
    k_gemm<64, 128, true><<<(N + 1) / 2, 256, 0, stream>>>(A, W3, b3, g3, be3, rm3, rv3, B, N);

    // Layer 4 (128->1): per-row dot, scalar gather-agg fused with bias + sigmoid(elu(.))
    k_dot128<<<nb((long)N * 32), 256, 0, stream>>>(B, W4, A, N);
    k_gather1_final<<<nb(N), 256, 0, stream>>>(base, cnt, csr_src, csr_w, dinv, A, b4, out, N);
}